// Round 1
// baseline (404.422 us; speedup 1.0000x reference)
//
#include <hip/hip_runtime.h>
#include <hip/hip_bf16.h>

typedef __hip_bfloat16 bf16;
typedef __attribute__((ext_vector_type(8))) short bf16x8;
typedef __attribute__((ext_vector_type(4))) float f32x4;

#define T_SEQ 2048
#define NHEADS 16
#define DK 64
#define DMODEL 1024

__device__ inline void load_lds16(const void* g, void* l) {
    __builtin_amdgcn_global_load_lds((const __attribute__((address_space(1))) void*)g,
                                     (__attribute__((address_space(3))) void*)l, 16, 0, 0);
}

// ---------------- fp32 -> bf16 convert ----------------
__global__ void cvt_kernel(const float* __restrict__ src, bf16* __restrict__ dst, int n) {
    int i = blockIdx.x * blockDim.x + threadIdx.x;
    int stride = gridDim.x * blockDim.x;
    for (; i < n; i += stride) dst[i] = __float2bfloat16(src[i]);
}

// ---------------- GEMM: C[M,N] = A[M,K] * B[N,K]^T (both bf16 row-major) ----------------
// 128x128 tile, BK=32, 256 threads = 4 waves in 2x2, each wave 64x64 (4x4 mfma 16x16x32)
template <bool WRITE_BF16>
__global__ __launch_bounds__(256) void gemm_bt(const bf16* __restrict__ A,
                                               const bf16* __restrict__ B,
                                               float* __restrict__ C,
                                               bf16* __restrict__ Cb,
                                               int M, int N, int K) {
    __shared__ bf16 As[128 * 32];
    __shared__ bf16 Bs[128 * 32];
    const int tid  = threadIdx.x;
    const int lane = tid & 63;
    const int wave = tid >> 6;
    const int l16  = lane & 15;
    const int quad = lane >> 4;
    const int wy = wave >> 1, wx = wave & 1;
    const int brow = blockIdx.y * 128;
    const int bcol = blockIdx.x * 128;

    f32x4 acc[4][4] = {};

    for (int k0 = 0; k0 < K; k0 += 32) {
        // stage 128x32 bf16 tiles: 512 chunks of 16B each, lds offset = chunk*16 (lane-linear)
#pragma unroll
        for (int i = 0; i < 2; ++i) {
            int j   = tid + 256 * i;
            int row = j >> 2;
            int cc  = j & 3;
            load_lds16(A + (size_t)(brow + row) * K + k0 + cc * 8, (char*)As + j * 16);
            load_lds16(B + (size_t)(bcol + row) * K + k0 + cc * 8, (char*)Bs + j * 16);
        }
        __syncthreads();
        bf16x8 af[4], bq[4];
#pragma unroll
        for (int i = 0; i < 4; ++i)
            af[i] = *(const bf16x8*)(As + (wy * 64 + i * 16 + l16) * 32 + quad * 8);
#pragma unroll
        for (int j = 0; j < 4; ++j)
            bq[j] = *(const bf16x8*)(Bs + (wx * 64 + j * 16 + l16) * 32 + quad * 8);
#pragma unroll
        for (int i = 0; i < 4; ++i)
#pragma unroll
            for (int j = 0; j < 4; ++j)
                acc[i][j] = __builtin_amdgcn_mfma_f32_16x16x32_bf16(af[i], bq[j], acc[i][j], 0, 0, 0);
        __syncthreads();
    }
    // epilogue: C/D layout col=lane&15, row=quad*4+reg
#pragma unroll
    for (int i = 0; i < 4; ++i)
#pragma unroll
        for (int j = 0; j < 4; ++j)
#pragma unroll
            for (int r = 0; r < 4; ++r) {
                int row = brow + wy * 64 + i * 16 + quad * 4 + r;
                int col = bcol + wx * 64 + j * 16 + l16;
                if (WRITE_BF16) Cb[(size_t)row * N + col] = __float2bfloat16(acc[i][j][r]);
                else            C[(size_t)row * N + col]  = acc[i][j][r];
            }
}

// ---------------- RoPE + head split/transpose ----------------
// qkv: [B*T][3072] bf16 (q|k|v). Writes qb,kb [B,H,T,dk] bf16 (rope'd), vt [B,H,dk,T] bf16.
__global__ void rope_split(const bf16* __restrict__ qkv,
                           bf16* __restrict__ qb, bf16* __restrict__ kb, bf16* __restrict__ vt) {
    int bt = blockIdx.x;          // 0..B*T-1
    int b  = bt >> 11;
    int t  = bt & (T_SEQ - 1);
    const bf16* row = qkv + (size_t)bt * 3072;
    int tid = threadIdx.x;
    // q and k rope pairs: 512 each
    for (int p = tid; p < 1024; p += 256) {
        int isK = p >> 9;
        int pp  = p & 511;
        int h   = pp >> 5;
        int i   = pp & 31;
        float inv = powf(1000.0f, -(float)i / 32.0f);
        float ang = (float)t * inv;
        float s, c;
        __sincosf(ang, &s, &c);
        int base = isK * 1024 + h * 64 + 2 * i;
        float xe = __bfloat162float(row[base]);
        float xo = __bfloat162float(row[base + 1]);
        float re = xe * c - xo * s;
        float ro = xe * s + xo * c;
        bf16* dst = isK ? kb : qb;
        size_t o = ((size_t)(b * NHEADS + h) * T_SEQ + t) * DK + 2 * i;
        dst[o]     = __float2bfloat16(re);
        dst[o + 1] = __float2bfloat16(ro);
    }
    // v transpose to [B,H,dk,T]
    for (int e = tid; e < 1024; e += 256) {
        int h = e >> 6, d = e & 63;
        vt[((size_t)(b * NHEADS + h) * DK + d) * T_SEQ + t] = row[2048 + e];
    }
}

// ---------------- flash attention (causal, online softmax) ----------------
// grid: (T/64, B*H); block 256 = 4 waves; each wave owns 16 query rows.
__global__ __launch_bounds__(256) void attn_kernel(const bf16* __restrict__ qb,
                                                   const bf16* __restrict__ kb,
                                                   const bf16* __restrict__ vt,
                                                   bf16* __restrict__ outc) {
    __shared__ bf16 Plds[4][16 * 32];
    int bh = blockIdx.y;
    int b = bh >> 4, h = bh & 15;
    int q0 = blockIdx.x * 64;
    int tid = threadIdx.x;
    int lane = tid & 63, wave = tid >> 6;
    int l16 = lane & 15, quad = lane >> 4;
    int qrow = q0 + wave * 16;

    const bf16* Qp = qb + ((size_t)bh * T_SEQ + qrow) * DK;
    const bf16* Kp = kb + (size_t)bh * T_SEQ * DK;
    const bf16* Vp = vt + (size_t)bh * DK * T_SEQ;

    // Q fragments (A-operand: m=lane&15, k=quad*8+j), 2 k-steps covering dk=64
    bf16x8 qf[2];
#pragma unroll
    for (int s = 0; s < 2; ++s)
        qf[s] = *(const bf16x8*)(Qp + (size_t)l16 * DK + s * 32 + quad * 8);

    f32x4 o[4] = {};
    float m_i[4], l_i[4];
#pragma unroll
    for (int r = 0; r < 4; ++r) { m_i[r] = -1e30f; l_i[r] = 0.0f; }

    const float scale = 0.125f; // 1/sqrt(64)
    int kend = q0 + 64;
    for (int k0 = 0; k0 < kend; k0 += 32) {
        // S = Q K^T for 32 keys (two 16-col mfma tiles, 2 dk-steps each)
        f32x4 sacc[2] = {};
#pragma unroll
        for (int nt = 0; nt < 2; ++nt)
#pragma unroll
            for (int ks = 0; ks < 2; ++ks) {
                bf16x8 kf = *(const bf16x8*)(Kp + (size_t)(k0 + nt * 16 + l16) * DK + ks * 32 + quad * 8);
                sacc[nt] = __builtin_amdgcn_mfma_f32_16x16x32_bf16(qf[ks], kf, sacc[nt], 0, 0, 0);
            }
        // online softmax per query row (C layout: row=quad*4+r, col=l16)
#pragma unroll
        for (int r = 0; r < 4; ++r) {
            int qi = qrow + quad * 4 + r;
            float v0 = sacc[0][r] * scale;
            float v1 = sacc[1][r] * scale;
            if (k0 + l16 > qi)      v0 = -1e30f;
            if (k0 + 16 + l16 > qi) v1 = -1e30f;
            float mx = fmaxf(v0, v1);
#pragma unroll
            for (int off = 1; off < 16; off <<= 1)
                mx = fmaxf(mx, __shfl_xor(mx, off));
            float mnew = fmaxf(m_i[r], mx);
            float p0 = __expf(v0 - mnew);
            float p1 = __expf(v1 - mnew);
            float alpha = __expf(m_i[r] - mnew);
            float ps = p0 + p1;
#pragma unroll
            for (int off = 1; off < 16; off <<= 1)
                ps += __shfl_xor(ps, off);
            l_i[r] = l_i[r] * alpha + ps;
            m_i[r] = mnew;
#pragma unroll
            for (int j = 0; j < 4; ++j) o[j][r] *= alpha;
            Plds[wave][(quad * 4 + r) * 32 + l16]      = __float2bfloat16(p0);
            Plds[wave][(quad * 4 + r) * 32 + 16 + l16] = __float2bfloat16(p1);
        }
        __syncthreads();
        // P (16x32) in A-layout; V fragment from vt (contiguous in t)
        bf16x8 pf = *(const bf16x8*)(&Plds[wave][l16 * 32 + quad * 8]);
#pragma unroll
        for (int j = 0; j < 4; ++j) {
            bf16x8 vf = *(const bf16x8*)(Vp + (size_t)(j * 16 + l16) * T_SEQ + k0 + quad * 8);
            o[j] = __builtin_amdgcn_mfma_f32_16x16x32_bf16(pf, vf, o[j], 0, 0, 0);
        }
        __syncthreads();
    }
    // write concat [B,T,H*dk] bf16
#pragma unroll
    for (int r = 0; r < 4; ++r) {
        int t = qrow + quad * 4 + r;
        float inv_l = 1.0f / l_i[r];
#pragma unroll
        for (int j = 0; j < 4; ++j)
            outc[((size_t)b * T_SEQ + t) * DMODEL + h * DK + j * 16 + l16] =
                __float2bfloat16(o[j][r] * inv_l);
    }
}

extern "C" void kernel_launch(void* const* d_in, const int* in_sizes, int n_in,
                              void* d_out, int out_size, void* d_ws, size_t ws_size,
                              hipStream_t stream) {
    const float* x  = (const float*)d_in[0];
    const float* wq = (const float*)d_in[1];
    const float* wk = (const float*)d_in[2];
    const float* wv = (const float*)d_in[3];
    const float* wo = (const float*)d_in[4];
    float* out = (float*)d_out;

    char* ws = (char*)d_ws;
    bf16* xb    = (bf16*)(ws);                      // 8 MiB  (4096x1024)
    bf16* wqkvb = (bf16*)(ws + (8ull << 20));       // 6 MiB  (3072x1024)
    bf16* wob   = (bf16*)(ws + (14ull << 20));      // 2 MiB  (1024x1024)
    bf16* qkv   = (bf16*)(ws + (16ull << 20));      // 24 MiB (4096x3072)
    bf16* qb    = (bf16*)(ws + (40ull << 20));      // 8 MiB
    bf16* kb    = (bf16*)(ws + (48ull << 20));      // 8 MiB
    bf16* vt    = (bf16*)(ws + (56ull << 20));      // 8 MiB
    bf16* conc  = (bf16*)(ws + (16ull << 20));      // reuse qkv region (8 MiB)

    cvt_kernel<<<4096, 256, 0, stream>>>(x,  xb, 4194304);
    cvt_kernel<<<1024, 256, 0, stream>>>(wq, wqkvb,           1048576);
    cvt_kernel<<<1024, 256, 0, stream>>>(wk, wqkvb + 1048576, 1048576);
    cvt_kernel<<<1024, 256, 0, stream>>>(wv, wqkvb + 2097152, 1048576);
    cvt_kernel<<<1024, 256, 0, stream>>>(wo, wob,             1048576);

    gemm_bt<true><<<dim3(24, 32), 256, 0, stream>>>(xb, wqkvb, nullptr, qkv, 4096, 3072, 1024);
    rope_split<<<4096, 256, 0, stream>>>(qkv, qb, kb, vt);
    attn_kernel<<<dim3(32, 32), 256, 0, stream>>>(qb, kb, vt, conc);
    gemm_bt<false><<<dim3(8, 32), 256, 0, stream>>>(conc, wob, out, nullptr, 4096, 1024, 1024);
}

// Round 3
// 319.880 us; speedup vs baseline: 1.2643x; 1.2643x over previous
//
#include <hip/hip_runtime.h>
#include <hip/hip_bf16.h>

typedef __hip_bfloat16 bf16;
typedef __attribute__((ext_vector_type(8))) short bf16x8;
typedef __attribute__((ext_vector_type(4))) float f32x4;

#define T_SEQ 2048
#define NHEADS 16
#define DK 64
#define DMODEL 1024

__device__ inline void load_lds16(const void* g, void* l) {
    __builtin_amdgcn_global_load_lds((const __attribute__((address_space(1))) void*)g,
                                     (__attribute__((address_space(3))) void*)l, 16, 0, 0);
}

// ---------------- fp32 -> bf16 convert ----------------
__global__ void cvt_kernel(const float* __restrict__ src, bf16* __restrict__ dst, int n) {
    int i = blockIdx.x * blockDim.x + threadIdx.x;
    int stride = gridDim.x * blockDim.x;
    for (; i < n; i += stride) dst[i] = __float2bfloat16(src[i]);
}

// all four 1024x1024 weights in one launch: wq|wk|wv -> wqkvb, wo -> wob
__global__ void cvt_w(const float* __restrict__ wq, const float* __restrict__ wk,
                      const float* __restrict__ wv, const float* __restrict__ wo,
                      bf16* __restrict__ wqkvb, bf16* __restrict__ wob) {
    int i = blockIdx.x * blockDim.x + threadIdx.x;   // 0 .. 4M-1
    const int M = 1 << 20;
    int seg = i >> 20, off = i & (M - 1);
    const float* src = (seg == 0) ? wq : (seg == 1) ? wk : (seg == 2) ? wv : wo;
    bf16* dst = (seg < 3) ? (wqkvb + (size_t)seg * M) : wob;
    dst[off] = __float2bfloat16(src[off]);
}

// ---------------- GEMM: C[M,N] = A[M,K] * B[N,K]^T (both bf16 row-major) ----------------
template <bool WRITE_BF16>
__global__ __launch_bounds__(256) void gemm_bt(const bf16* __restrict__ A,
                                               const bf16* __restrict__ B,
                                               float* __restrict__ C,
                                               bf16* __restrict__ Cb,
                                               int M, int N, int K) {
    __shared__ bf16 As[128 * 32];
    __shared__ bf16 Bs[128 * 32];
    const int tid  = threadIdx.x;
    const int lane = tid & 63;
    const int wave = tid >> 6;
    const int l16  = lane & 15;
    const int quad = lane >> 4;
    const int wy = wave >> 1, wx = wave & 1;
    const int brow = blockIdx.y * 128;
    const int bcol = blockIdx.x * 128;

    f32x4 acc[4][4] = {};

    for (int k0 = 0; k0 < K; k0 += 32) {
#pragma unroll
        for (int i = 0; i < 2; ++i) {
            int j   = tid + 256 * i;
            int row = j >> 2;
            int cc  = j & 3;
            load_lds16(A + (size_t)(brow + row) * K + k0 + cc * 8, (char*)As + j * 16);
            load_lds16(B + (size_t)(bcol + row) * K + k0 + cc * 8, (char*)Bs + j * 16);
        }
        __syncthreads();
        bf16x8 af[4], bq[4];
#pragma unroll
        for (int i = 0; i < 4; ++i)
            af[i] = *(const bf16x8*)(As + (wy * 64 + i * 16 + l16) * 32 + quad * 8);
#pragma unroll
        for (int j = 0; j < 4; ++j)
            bq[j] = *(const bf16x8*)(Bs + (wx * 64 + j * 16 + l16) * 32 + quad * 8);
#pragma unroll
        for (int i = 0; i < 4; ++i)
#pragma unroll
            for (int j = 0; j < 4; ++j)
                acc[i][j] = __builtin_amdgcn_mfma_f32_16x16x32_bf16(af[i], bq[j], acc[i][j], 0, 0, 0);
        __syncthreads();
    }
#pragma unroll
    for (int i = 0; i < 4; ++i)
#pragma unroll
        for (int j = 0; j < 4; ++j)
#pragma unroll
            for (int r = 0; r < 4; ++r) {
                int row = brow + wy * 64 + i * 16 + quad * 4 + r;
                int col = bcol + wx * 64 + j * 16 + l16;
                if (WRITE_BF16) Cb[(size_t)row * N + col] = __float2bfloat16(acc[i][j][r]);
                else            C[(size_t)row * N + col]  = acc[i][j][r];
            }
}

// ---------------- RoPE + head split/transpose ----------------
__global__ void rope_split(const bf16* __restrict__ qkv,
                           bf16* __restrict__ qb, bf16* __restrict__ kb, bf16* __restrict__ vt) {
    int bt = blockIdx.x;
    int b  = bt >> 11;
    int t  = bt & (T_SEQ - 1);
    const bf16* row = qkv + (size_t)bt * 3072;
    int tid = threadIdx.x;
    for (int p = tid; p < 1024; p += 256) {
        int isK = p >> 9;
        int pp  = p & 511;
        int h   = pp >> 5;
        int i   = pp & 31;
        // 1000^(-i/32) = exp2(-i * log2(1000)/32)
        float inv = exp2f(-0.31143075889f * (float)i);
        float ang = (float)t * inv;
        float s, c;
        __sincosf(ang, &s, &c);
        int base = isK * 1024 + h * 64 + 2 * i;
        float xe = __bfloat162float(row[base]);
        float xo = __bfloat162float(row[base + 1]);
        float re = xe * c - xo * s;
        float ro = xe * s + xo * c;
        bf16* dst = isK ? kb : qb;
        size_t o = ((size_t)(b * NHEADS + h) * T_SEQ + t) * DK + 2 * i;
        dst[o]     = __float2bfloat16(re);
        dst[o + 1] = __float2bfloat16(ro);
    }
    for (int e = tid; e < 1024; e += 256) {
        int h = e >> 6, d = e & 63;
        vt[((size_t)(b * NHEADS + h) * DK + d) * T_SEQ + t] = row[2048 + e];
    }
}

// ---------------- flash attention v2 ----------------
// S^T formulation: per-lane softmax state for query = lane&15. No block barriers
// (P transpose LDS buffer is per-wave; compiler inserts lgkmcnt waits).
// Causal balance: block handles tiles (x, 31-x); waves 0-3 -> tile x, waves 4-7 -> tile 31-x.
#define PSTRIDE 72   // bf16 units; 144 B rows: 16B-aligned b128 reads, 2-way-max bank aliasing
__global__ __launch_bounds__(512) void attn_kernel(const bf16* __restrict__ qb,
                                                   const bf16* __restrict__ kb,
                                                   const bf16* __restrict__ vt,
                                                   bf16* __restrict__ outc) {
    __shared__ bf16 Pl[8][16 * PSTRIDE];
    const int bh = blockIdx.y;
    const int b = bh >> 4, h = bh & 15;
    const int tid = threadIdx.x;
    const int lane = tid & 63, wave = tid >> 6;
    const int l16 = lane & 15, quad = lane >> 4;
    const int tile = (wave < 4) ? blockIdx.x : (31 - blockIdx.x);
    const int qrow = tile * 64 + (wave & 3) * 16;

    const bf16* Qp = qb + (size_t)bh * T_SEQ * DK;
    const bf16* Kp = kb + (size_t)bh * T_SEQ * DK;
    const bf16* Vp = vt + (size_t)bh * DK * T_SEQ;
    bf16* Pw = &Pl[wave][0];

    // Q as B-operand: n = query = l16, k = dk = quad*8+j (+32 per kstep)
    bf16x8 qf[2];
#pragma unroll
    for (int s = 0; s < 2; ++s)
        qf[s] = *(const bf16x8*)(Qp + (size_t)(qrow + l16) * DK + s * 32 + quad * 8);

    f32x4 o[4] = {};
    float m_i = -1e30f, l_i = 0.0f;
    const float ksc = 0.18033688011112042f;  // (1/sqrt(64)) * log2(e), exp2-domain softmax

    const int nfull = qrow >> 6;   // steps with no masking needed
    for (int it = 0; it <= nfull; ++it) {
        const int k0 = it * 64;
        const bool masked = (it == nfull);
        // S^T = K Q^T over 64 keys: 4 key-tiles x 2 dk-steps
        f32x4 sacc[4] = {};
#pragma unroll
        for (int nt = 0; nt < 4; ++nt)
#pragma unroll
            for (int ks = 0; ks < 2; ++ks) {
                bf16x8 kf = *(const bf16x8*)(Kp + (size_t)(k0 + nt * 16 + l16) * DK + ks * 32 + quad * 8);
                sacc[nt] = __builtin_amdgcn_mfma_f32_16x16x32_bf16(kf, qf[ks], sacc[nt], 0, 0, 0);
            }
        // lane holds S^T[key = k0+nt*16+quad*4+r][query = qrow+l16]
        float s2[4][4];
        float mx = -1e30f;
#pragma unroll
        for (int nt = 0; nt < 4; ++nt)
#pragma unroll
            for (int r = 0; r < 4; ++r) {
                float v = sacc[nt][r] * ksc;
                if (masked && (k0 + nt * 16 + quad * 4 + r > qrow + l16)) v = -1e30f;
                s2[nt][r] = v;
                mx = fmaxf(mx, v);
            }
        mx = fmaxf(mx, __shfl_xor(mx, 16));
        mx = fmaxf(mx, __shfl_xor(mx, 32));
        const float mnew = fmaxf(m_i, mx);
        const float alpha = exp2f(m_i - mnew);
        float ps = 0.0f;
#pragma unroll
        for (int nt = 0; nt < 4; ++nt) {
            union { bf16 hv[4]; uint2 u; } pk;
#pragma unroll
            for (int r = 0; r < 4; ++r) {
                float p = exp2f(s2[nt][r] - mnew);
                ps += p;
                pk.hv[r] = __float2bfloat16(p);
            }
            *(uint2*)(Pw + l16 * PSTRIDE + nt * 16 + quad * 4) = pk.u;
        }
        ps += __shfl_xor(ps, 16);
        ps += __shfl_xor(ps, 32);
        l_i = l_i * alpha + ps;
        m_i = mnew;
        // o is in C-layout (row = query = quad*4+r): fetch that query's alpha
        float ar[4];
#pragma unroll
        for (int r = 0; r < 4; ++r) ar[r] = __shfl(alpha, quad * 4 + r);
#pragma unroll
        for (int j = 0; j < 4; ++j)
#pragma unroll
            for (int r = 0; r < 4; ++r) o[j][r] *= ar[r];
        // PV: P in A-layout from LDS, V^T fragments contiguous in t
#pragma unroll
        for (int ks = 0; ks < 2; ++ks) {
            bf16x8 pf = *(const bf16x8*)(Pw + l16 * PSTRIDE + ks * 32 + quad * 8);
#pragma unroll
            for (int j = 0; j < 4; ++j) {
                bf16x8 vf = *(const bf16x8*)(Vp + (size_t)(j * 16 + l16) * T_SEQ + k0 + ks * 32 + quad * 8);
                o[j] = __builtin_amdgcn_mfma_f32_16x16x32_bf16(pf, vf, o[j], 0, 0, 0);
            }
        }
    }
    // epilogue: query = qrow+quad*4+r, dk = j*16+l16; l_i lives at lane (query&15)
#pragma unroll
    for (int r = 0; r < 4; ++r) {
        float lr = __shfl(l_i, quad * 4 + r);
        float inv_l = 1.0f / lr;
        int t = qrow + quad * 4 + r;
#pragma unroll
        for (int j = 0; j < 4; ++j)
            outc[((size_t)b * T_SEQ + t) * DMODEL + h * DK + j * 16 + l16] =
                __float2bfloat16(o[j][r] * inv_l);
    }
}

extern "C" void kernel_launch(void* const* d_in, const int* in_sizes, int n_in,
                              void* d_out, int out_size, void* d_ws, size_t ws_size,
                              hipStream_t stream) {
    const float* x  = (const float*)d_in[0];
    const float* wq = (const float*)d_in[1];
    const float* wk = (const float*)d_in[2];
    const float* wv = (const float*)d_in[3];
    const float* wo = (const float*)d_in[4];
    float* out = (float*)d_out;

    char* ws = (char*)d_ws;
    bf16* xb    = (bf16*)(ws);                      // 8 MiB  (4096x1024)
    bf16* wqkvb = (bf16*)(ws + (8ull << 20));       // 6 MiB  (3072x1024)
    bf16* wob   = (bf16*)(ws + (14ull << 20));      // 2 MiB  (1024x1024)
    bf16* qkv   = (bf16*)(ws + (16ull << 20));      // 24 MiB (4096x3072)
    bf16* qb    = (bf16*)(ws + (40ull << 20));      // 8 MiB
    bf16* kb    = (bf16*)(ws + (48ull << 20));      // 8 MiB
    bf16* vt    = (bf16*)(ws + (56ull << 20));      // 8 MiB
    bf16* conc  = (bf16*)(ws + (16ull << 20));      // reuse qkv region (8 MiB)

    cvt_kernel<<<4096, 256, 0, stream>>>(x, xb, 4194304);
    cvt_w<<<16384, 256, 0, stream>>>(wq, wk, wv, wo, wqkvb, wob);

    gemm_bt<true><<<dim3(24, 32), 256, 0, stream>>>(xb, wqkvb, nullptr, qkv, 4096, 3072, 1024);
    rope_split<<<4096, 256, 0, stream>>>(qkv, qb, kb, vt);
    attn_kernel<<<dim3(16, 32), 512, 0, stream>>>(qb, kb, vt, conc);
    gemm_bt<false><<<dim3(8, 32), 256, 0, stream>>>(conc, wob, out, nullptr, 4096, 1024, 1024);
}